// Round 12
// baseline (750.452 us; speedup 1.0000x reference)
//
#include <hip/hip_runtime.h>
#include <hip/hip_bf16.h>
#include <hip/hip_cooperative_groups.h>

namespace cg = cooperative_groups;

// Problem constants
#define B_  4
#define S_  1024
#define D_  1024
#define H_  16
#define HD_ 64

typedef __bf16 bf16;
typedef __bf16 bf16x8 __attribute__((ext_vector_type(8)));
typedef __bf16 bf16x4 __attribute__((ext_vector_type(4)));
typedef float  f32x4  __attribute__((ext_vector_type(4)));

// ===========================================================================
// Phase bodies (shared between the fused cooperative kernel and the
// standalone fallback kernels). Logic identical to round 11.
// ===========================================================================

// ---- convert: one vec8 unit of [q|k|v|Wq|Wk|Wv|Wo] fp32 -> bf16 ----------
__device__ __forceinline__ void convert_body(
    size_t u, const float* __restrict__ q, const float* __restrict__ k,
    const float* __restrict__ v, const float* __restrict__ Wq,
    const float* __restrict__ Wk, const float* __restrict__ Wv,
    const float* __restrict__ Wo, bf16* __restrict__ Xb, bf16* __restrict__ Wall)
{
    const size_t e  = u * 8;
    const size_t M4 = (size_t)1 << 22;
    const float* s;
    bf16* d;
    if (e < 3 * M4) {
        const int which = (int)(e >> 22);
        s = ((which == 0) ? q : (which == 1) ? k : v) + (e - ((size_t)which << 22));
        d = Xb + e;
    } else {
        const size_t r = e - 3 * M4;
        const int which = (int)(r >> 20);
        s = ((which == 0) ? Wq : (which == 1) ? Wk : (which == 2) ? Wv : Wo) +
            (r - ((size_t)which << 20));
        d = Wall + r;
    }
    const f32x4 a = *(const f32x4*)s;
    const f32x4 b = *(const f32x4*)(s + 4);
    bf16x8 o;
#pragma unroll
    for (int jj = 0; jj < 4; ++jj) { o[jj] = (bf16)a[jj]; o[jj + 4] = (bf16)b[jj]; }
    *(bf16x8*)d = o;
}

// ---- qkv projection (bf16 x bf16, register-prefetch, 768 blocks) ----------
__device__ __forceinline__ void qkv_body(
    char* smem, int blk, const bf16* __restrict__ Xb, const bf16* __restrict__ Wall,
    const float* __restrict__ bq, const float* __restrict__ bk,
    const float* __restrict__ bv,
    bf16* __restrict__ Qh, bf16* __restrict__ Kh, bf16* __restrict__ Vt)
{
    bf16* sA = (bf16*)smem;              // 128*32 = 8 KB
    bf16* sB = (bf16*)(smem + 8192);     // 128*32 = 8 KB

    const int mIdx = blk & 31;           // b = (z*8+nIdx)*32 + mIdx
    const int t    = blk >> 5;
    const int nIdx = t & 7;
    const int z    = t >> 3;

    const int m0 = mIdx * 128, n0 = nIdx * 128;
    const bf16* __restrict__ X = Xb + ((size_t)z << 22);
    const bf16* __restrict__ W = Wall + ((size_t)z << 20);
    const float* __restrict__ bias = (z == 0) ? bq : (z == 1) ? bk : bv;

    const int tid  = threadIdx.x;
    const int lane = tid & 63;
    const int wave = tid >> 6;
    const int lr   = lane & 15;
    const int lg   = lane >> 4;
    const int mw   = (wave >> 1) * 64;
    const int nw   = (wave & 1) * 64;
    const int srow = tid >> 2;
    const int skg  = (tid & 3) * 8;

    f32x4 acc[4][4];
#pragma unroll
    for (int i = 0; i < 4; ++i)
#pragma unroll
        for (int j = 0; j < 4; ++j) acc[i][j] = (f32x4){0.f, 0.f, 0.f, 0.f};

    const bf16* Ab = X + (size_t)(m0 + srow) * D_ + skg;
    const bf16* Wb = W + (size_t)(n0 + srow) * D_ + skg;

    bf16x8 ra[2], rb[2];
#pragma unroll
    for (int p = 0; p < 2; ++p) {
        ra[p] = *(const bf16x8*)(Ab + (size_t)(p * 64) * D_);
        rb[p] = *(const bf16x8*)(Wb + (size_t)(p * 64) * D_);
    }

    for (int kt = 0; kt < 32; ++kt) {
        __syncthreads();
#pragma unroll
        for (int p = 0; p < 2; ++p) {
            *(bf16x8*)(sA + p * 2048 + tid * 8) = ra[p];
            *(bf16x8*)(sB + p * 2048 + tid * 8) = rb[p];
        }
        __syncthreads();

        if (kt < 31) {
            const int k1 = (kt + 1) * 32;
#pragma unroll
            for (int p = 0; p < 2; ++p) {
                ra[p] = *(const bf16x8*)(Ab + (size_t)(p * 64) * D_ + k1);
                rb[p] = *(const bf16x8*)(Wb + (size_t)(p * 64) * D_ + k1);
            }
        }

        bf16x8 af[4], bfr[4];
#pragma unroll
        for (int i = 0; i < 4; ++i)
            af[i] = *(const bf16x8*)(sA + (mw + 16 * i + lr) * 32 + lg * 8);
#pragma unroll
        for (int j = 0; j < 4; ++j)
            bfr[j] = *(const bf16x8*)(sB + (nw + 16 * j + lr) * 32 + lg * 8);
#pragma unroll
        for (int i = 0; i < 4; ++i)
#pragma unroll
            for (int j = 0; j < 4; ++j)
                acc[i][j] = __builtin_amdgcn_mfma_f32_16x16x32_bf16(af[i], bfr[j],
                                                                    acc[i][j], 0, 0, 0);
    }

    // Epilogue. C-layout: m = base+lg*4+r, n = base+lr. Q pre-scaled by 1/8.
    if (z < 2) {
        bf16* dst = (z == 0) ? Qh : Kh;
        const float sc = (z == 0) ? 0.125f : 1.0f;
#pragma unroll
        for (int i = 0; i < 4; ++i) {
#pragma unroll
            for (int j = 0; j < 4; ++j) {
                const int n = n0 + nw + 16 * j + lr;
                const int h = n >> 6, d = n & 63;
                const float bn = bias[n];
                const float dv_rev = 0.15915494309189535f *
                    exp2f(-(float)(d & ~1) * 0.20762050593046648f);
#pragma unroll
                for (int r = 0; r < 4; ++r) {
                    const int m = m0 + mw + 16 * i + lg * 4 + r;
                    const int b = m >> 10, s = m & 1023;
                    float rev = (float)s * dv_rev;
                    rev -= floorf(rev);                       // [0,1) revolutions
                    const float sv = __builtin_amdgcn_sinf(rev);
                    const float cv = __builtin_amdgcn_cosf(rev);
                    const float pe  = (d & 1) ? cv : sv;
                    const float val = (acc[i][j][r] + bn + pe) * sc;
                    dst[(size_t)((b * H_ + h) * S_ + s) * HD_ + d] = (bf16)val;
                }
            }
        }
    } else {
#pragma unroll
        for (int i = 0; i < 4; ++i) {
            const int mb = m0 + mw + 16 * i + lg * 4;
            const int b = mb >> 10, sb = mb & 1023;
#pragma unroll
            for (int j = 0; j < 4; ++j) {
                const int n = n0 + nw + 16 * j + lr;
                const int h = n >> 6, d = n & 63;
                const float bn = bias[n];
                bf16x4 pk;
#pragma unroll
                for (int r = 0; r < 4; ++r) pk[r] = (bf16)(acc[i][j][r] + bn);
                *(bf16x4*)(Vt + (size_t)((b * H_ + h) * HD_ + d) * S_ + sb) = pk;
            }
        }
    }
}

// ---- flash attention (r8/r11 version; 512 blocks of 4 waves) --------------
#define LDK 72
__device__ __forceinline__ void attn_body(
    char* smem, int blk, const bf16* __restrict__ Qh, const bf16* __restrict__ Kh,
    const bf16* __restrict__ Vt, bf16* __restrict__ att)
{
    bf16* sK = (bf16*)smem;                 // 64*72*2  = 9216 B
    bf16* sV = (bf16*)(smem + 9216);        // 9216 B
    bf16* sP = (bf16*)(smem + 18432);       // 4*32*72*2 = 18432 B

    const int tid  = threadIdx.x;
    const int lane = tid & 63;
    const int wave = tid >> 6;
    const int lr   = lane & 15;
    const int lg   = lane >> 4;
    const int bh   = blk & 63;              // low bits -> XCD locality
    const int qt   = blk >> 6;              // 0..7
    const int qw   = qt * 128 + wave * 32;

    const bf16* Qb = Qh + (size_t)bh * S_ * HD_;
    const bf16* Kb = Kh + (size_t)bh * S_ * HD_;
    const bf16* Vb = Vt + (size_t)bh * HD_ * S_;

    bf16x8 qa[2][2];
#pragma unroll
    for (int i = 0; i < 2; ++i)
#pragma unroll
        for (int ks = 0; ks < 2; ++ks)
            qa[i][ks] = *(const bf16x8*)(Qb + (size_t)(qw + 16 * i + lr) * HD_ +
                                         ks * 32 + lg * 8);

    f32x4 o[2][4];
    float lsum[2][4];
#pragma unroll
    for (int i = 0; i < 2; ++i) {
#pragma unroll
        for (int jd = 0; jd < 4; ++jd) o[i][jd] = (f32x4){0.f, 0.f, 0.f, 0.f};
#pragma unroll
        for (int r = 0; r < 4; ++r) lsum[i][r] = 0.f;
    }

    bf16* const pw   = sP + wave * 32 * LDK;
    const int  srow  = tid >> 3;
    const int  scol  = (tid & 7) * 8;

    bf16x8 kv[2], vv[2];
#pragma unroll
    for (int p = 0; p < 2; ++p) {
        kv[p] = *(const bf16x8*)(Kb + (size_t)(p * 32 + srow) * HD_ + scol);
        vv[p] = *(const bf16x8*)(Vb + (size_t)(p * 32 + srow) * S_ + scol);
    }

    for (int kc = 0; kc < 16; ++kc) {
        __syncthreads();
#pragma unroll
        for (int p = 0; p < 2; ++p) {
            *(bf16x8*)(sK + (p * 32 + srow) * LDK + scol) = kv[p];
            *(bf16x8*)(sV + (p * 32 + srow) * LDK + scol) = vv[p];
        }
        __syncthreads();

        if (kc < 15) {
            const int kn = (kc + 1) * 64;
#pragma unroll
            for (int p = 0; p < 2; ++p) {
                kv[p] = *(const bf16x8*)(Kb + (size_t)(kn + p * 32 + srow) * HD_ + scol);
                vv[p] = *(const bf16x8*)(Vb + (size_t)(p * 32 + srow) * S_ + kn + scol);
            }
        }

        bf16x8 kb[4][2];
#pragma unroll
        for (int jk = 0; jk < 4; ++jk)
#pragma unroll
            for (int ks = 0; ks < 2; ++ks)
                kb[jk][ks] = *(const bf16x8*)(sK + (16 * jk + lr) * LDK + ks * 32 + lg * 8);

#pragma unroll
        for (int i = 0; i < 2; ++i)
#pragma unroll
            for (int jk = 0; jk < 4; ++jk) {
                f32x4 s = (f32x4){0.f, 0.f, 0.f, 0.f};
                s = __builtin_amdgcn_mfma_f32_16x16x32_bf16(qa[i][0], kb[jk][0], s, 0, 0, 0);
                s = __builtin_amdgcn_mfma_f32_16x16x32_bf16(qa[i][1], kb[jk][1], s, 0, 0, 0);
#pragma unroll
                for (int r = 0; r < 4; ++r) {
                    const float pp = __expf(s[r]);    // Q pre-scaled by 1/8
                    lsum[i][r] += pp;
                    pw[(16 * i + lg * 4 + r) * LDK + 16 * jk + lr] = (bf16)pp;
                }
            }
        asm volatile("s_waitcnt lgkmcnt(0)" ::: "memory");  // wave-private region

#pragma unroll
        for (int ks = 0; ks < 2; ++ks) {
            bf16x8 pa[2];
#pragma unroll
            for (int i = 0; i < 2; ++i)
                pa[i] = *(const bf16x8*)(pw + (16 * i + lr) * LDK + ks * 32 + lg * 8);
#pragma unroll
            for (int jd = 0; jd < 4; ++jd) {
                const bf16x8 vb = *(const bf16x8*)(sV + (16 * jd + lr) * LDK +
                                                   ks * 32 + lg * 8);
#pragma unroll
                for (int i = 0; i < 2; ++i)
                    o[i][jd] = __builtin_amdgcn_mfma_f32_16x16x32_bf16(pa[i], vb,
                                                                       o[i][jd], 0, 0, 0);
            }
        }
    }

    const int b = bh >> 4, h = bh & 15;
#pragma unroll
    for (int i = 0; i < 2; ++i)
#pragma unroll
        for (int r = 0; r < 4; ++r) {
            float l = lsum[i][r];
#pragma unroll
            for (int off = 1; off < 16; off <<= 1)
                l += __shfl_xor(l, off, 64);
            const float inv = 1.f / l;
            const int s = qw + 16 * i + lg * 4 + r;
#pragma unroll
            for (int jd = 0; jd < 4; ++jd) {
                const int d = 16 * jd + lr;
                att[(size_t)(b * S_ + s) * D_ + h * HD_ + d] = (bf16)(o[i][jd][r] * inv);
            }
        }
}

// ---- output projection (64x128 tile, 512 blocks, reg-prefetch) ------------
__device__ __forceinline__ void out_body(
    char* smem, int blk, const bf16* __restrict__ A, const bf16* __restrict__ Wob,
    const float* __restrict__ bo, float* __restrict__ out)
{
    bf16* sA = (bf16*)smem;                 // 64*32*2 = 4096 B
    bf16* sB = (bf16*)(smem + 4096);        // 128*32*2 = 8192 B

    const int mIdx = blk & 63;              // b = nIdx*64 + mIdx
    const int nIdx = blk >> 6;
    const int m0 = mIdx * 64, n0 = nIdx * 128;

    const int tid  = threadIdx.x;
    const int lane = tid & 63;
    const int wave = tid >> 6;
    const int lr   = lane & 15;
    const int lg   = lane >> 4;
    const int mw   = (wave >> 1) * 32;
    const int nw   = (wave & 1) * 64;
    const int srow = tid >> 2;
    const int skg  = (tid & 3) * 8;

    f32x4 acc[2][4];
#pragma unroll
    for (int i = 0; i < 2; ++i)
#pragma unroll
        for (int j = 0; j < 4; ++j) acc[i][j] = (f32x4){0.f, 0.f, 0.f, 0.f};

    const bf16* Ab = A   + (size_t)(m0 + srow) * D_ + skg;
    const bf16* Wb = Wob + (size_t)(n0 + srow) * D_ + skg;

    bf16x8 aa, wb[2];
    aa = *(const bf16x8*)(Ab);
#pragma unroll
    for (int p = 0; p < 2; ++p)
        wb[p] = *(const bf16x8*)(Wb + (size_t)(p * 64) * D_);

    for (int kt = 0; kt < 32; ++kt) {
        __syncthreads();
        *(bf16x8*)(sA + tid * 8) = aa;
#pragma unroll
        for (int p = 0; p < 2; ++p)
            *(bf16x8*)(sB + p * 2048 + tid * 8) = wb[p];
        __syncthreads();

        if (kt < 31) {
            const int k1 = (kt + 1) * 32;
            aa = *(const bf16x8*)(Ab + k1);
#pragma unroll
            for (int p = 0; p < 2; ++p)
                wb[p] = *(const bf16x8*)(Wb + (size_t)(p * 64) * D_ + k1);
        }

        bf16x8 af[2], bfr[4];
#pragma unroll
        for (int i = 0; i < 2; ++i)
            af[i] = *(const bf16x8*)(sA + (mw + 16 * i + lr) * 32 + lg * 8);
#pragma unroll
        for (int j = 0; j < 4; ++j)
            bfr[j] = *(const bf16x8*)(sB + (nw + 16 * j + lr) * 32 + lg * 8);
#pragma unroll
        for (int i = 0; i < 2; ++i)
#pragma unroll
            for (int j = 0; j < 4; ++j)
                acc[i][j] = __builtin_amdgcn_mfma_f32_16x16x32_bf16(af[i], bfr[j],
                                                                    acc[i][j], 0, 0, 0);
    }

#pragma unroll
    for (int i = 0; i < 2; ++i)
#pragma unroll
        for (int j = 0; j < 4; ++j) {
            const int n = n0 + nw + 16 * j + lr;
            const float bn = bo[n];
#pragma unroll
            for (int r = 0; r < 4; ++r) {
                const int m = m0 + mw + 16 * i + lg * 4 + r;
                out[(size_t)m * D_ + n] = acc[i][j][r] + bn;   // fp32 store
            }
        }
}

// ===========================================================================
// Fused cooperative kernel: convert -> qkv -> attn -> out_proj with
// grid.sync() between phases. Grid 768 x 256; __launch_bounds__(256,3)
// guarantees 3 blocks/CU (LDS 36.9KB x 3 = 110.6 <= 160 KB; VGPR <= 170).
// Eliminates ~3 inter-dispatch gaps (~60 us measured at r11).
// ===========================================================================
__global__ __launch_bounds__(256, 3)
void fused_kernel(const float* __restrict__ q, const float* __restrict__ k,
                  const float* __restrict__ v,
                  const float* __restrict__ Wq, const float* __restrict__ Wk,
                  const float* __restrict__ Wv, const float* __restrict__ Wo,
                  const float* __restrict__ bq, const float* __restrict__ bk,
                  const float* __restrict__ bv, const float* __restrict__ bo,
                  bf16* __restrict__ Xb, bf16* __restrict__ Wall,
                  bf16* __restrict__ Qh, bf16* __restrict__ Kh,
                  bf16* __restrict__ Vt, bf16* __restrict__ att,
                  float* __restrict__ out)
{
    __shared__ __align__(16) char smem[36864];
    cg::grid_group grid = cg::this_grid();

    // Phase 0: convert (grid-stride over 2M vec8 units = 16M elems)
    {
        const size_t total8 = (size_t)2 * 1024 * 1024;
        for (size_t u = (size_t)blockIdx.x * 256 + threadIdx.x; u < total8;
             u += (size_t)768 * 256)
            convert_body(u, q, k, v, Wq, Wk, Wv, Wo, Xb, Wall);
    }
    __threadfence();
    grid.sync();

    // Phase 1: qkv projection (exactly 768 tile-blocks)
    qkv_body(smem, blockIdx.x, Xb, Wall, bq, bk, bv, Qh, Kh, Vt);
    __threadfence();
    grid.sync();

    // Phase 2: attention (512 units; blocks 512..767 idle through the sync)
    if (blockIdx.x < 512)
        attn_body(smem, blockIdx.x, Qh, Kh, Vt, att);
    __threadfence();
    grid.sync();

    // Phase 3: output projection (512 units)
    if (blockIdx.x < 512)
        out_body(smem, blockIdx.x, att, Wall + ((size_t)3 << 20), bo, out);
}

// ===========================================================================
// Standalone fallback kernels (r11 path) — used if cooperative launch fails.
// ===========================================================================
__global__ __launch_bounds__(256)
void convert_all_kernel(const float* __restrict__ q, const float* __restrict__ k,
                        const float* __restrict__ v,
                        const float* __restrict__ Wq, const float* __restrict__ Wk,
                        const float* __restrict__ Wv, const float* __restrict__ Wo,
                        bf16* __restrict__ Xb, bf16* __restrict__ Wall)
{
    convert_body((size_t)blockIdx.x * 256 + threadIdx.x, q, k, v, Wq, Wk, Wv, Wo,
                 Xb, Wall);
}

__global__ __launch_bounds__(256)
void qkv_proj_kernel(const bf16* __restrict__ Xb, const bf16* __restrict__ Wall,
                     const float* __restrict__ bq, const float* __restrict__ bk,
                     const float* __restrict__ bv,
                     bf16* __restrict__ Qh, bf16* __restrict__ Kh,
                     bf16* __restrict__ Vt)
{
    __shared__ __align__(16) char smem[16384];
    qkv_body(smem, blockIdx.x, Xb, Wall, bq, bk, bv, Qh, Kh, Vt);
}

__global__ __launch_bounds__(256)
void attn_kernel(const bf16* __restrict__ Qh, const bf16* __restrict__ Kh,
                 const bf16* __restrict__ Vt, bf16* __restrict__ att)
{
    __shared__ __align__(16) char smem[36864];
    attn_body(smem, blockIdx.x, Qh, Kh, Vt, att);
}

__global__ __launch_bounds__(256)
void out_proj_kernel(const bf16* __restrict__ A, const bf16* __restrict__ Wob,
                     const float* __restrict__ bo, float* __restrict__ out)
{
    __shared__ __align__(16) char smem[12288];
    out_body(smem, blockIdx.x, A, Wob, bo, out);
}

extern "C" void kernel_launch(void* const* d_in, const int* in_sizes, int n_in,
                              void* d_out, int out_size, void* d_ws, size_t ws_size,
                              hipStream_t stream)
{
    const float* q  = (const float*)d_in[0];
    const float* k  = (const float*)d_in[1];
    const float* v  = (const float*)d_in[2];
    const float* Wq = (const float*)d_in[3];
    const float* bq = (const float*)d_in[4];
    const float* Wk = (const float*)d_in[5];
    const float* bk = (const float*)d_in[6];
    const float* Wv = (const float*)d_in[7];
    const float* bv = (const float*)d_in[8];
    const float* Wo = (const float*)d_in[9];
    const float* bo = (const float*)d_in[10];

    char* ws = (char*)d_ws;
    const size_t MB8 = (size_t)8 * 1024 * 1024;
    bf16* Qh   = (bf16*)(ws);
    bf16* Kh   = (bf16*)(ws + MB8);
    bf16* Vt   = (bf16*)(ws + 2 * MB8);
    bf16* att  = (bf16*)(ws + 3 * MB8);
    bf16* Xb   = (bf16*)(ws + 4 * MB8);            // 24 MB: [q|k|v]
    bf16* Wall = (bf16*)(ws + 7 * MB8);            // 8 MB: [Wq|Wk|Wv|Wo]
    float* outp = (float*)d_out;

    void* args[] = {
        (void*)&q, (void*)&k, (void*)&v, (void*)&Wq, (void*)&Wk, (void*)&Wv,
        (void*)&Wo, (void*)&bq, (void*)&bk, (void*)&bv, (void*)&bo,
        (void*)&Xb, (void*)&Wall, (void*)&Qh, (void*)&Kh, (void*)&Vt,
        (void*)&att, (void*)&outp
    };
    hipError_t err = hipLaunchCooperativeKernel((const void*)fused_kernel,
                                                dim3(768), dim3(256), args, 0,
                                                stream);
    if (err != hipSuccess) {
        // Fallback: r11 four-dispatch path (identical math).
        convert_all_kernel<<<8192, 256, 0, stream>>>(q, k, v, Wq, Wk, Wv, Wo,
                                                     Xb, Wall);
        qkv_proj_kernel<<<768, 256, 0, stream>>>(Xb, Wall, bq, bk, bv, Qh, Kh, Vt);
        attn_kernel<<<512, 256, 0, stream>>>(Qh, Kh, Vt, att);
        out_proj_kernel<<<512, 256, 0, stream>>>(att, Wall + ((size_t)3 << 20),
                                                 bo, outp);
    }
}